// Round 2
// 287.896 us; speedup vs baseline: 1.0231x; 1.0231x over previous
//
#include <hip/hip_runtime.h>
#include <hip/hip_bf16.h>

// Problem constants (2,8,2048,64) fp32 -> (2,8,2048,2048) fp32
#define SEQ 2048
#define NH  64
#define KP  128      // packed K = 2*NH (cos | sin)
#define NBATCH 16    // 2*8
#define STLD 68      // f32 epilogue-staging row stride: 17 float4s -> every row 16B-aligned,
                     // ds_write 2-way banks (free), ds_read_b128 uniform 8/bank (no excess)
#define STSZ (16 * STLD)   // floats per staging slab (one 16x64 C sub-tile)

typedef __attribute__((ext_vector_type(8))) short  short8;   // 8 bf16 (4 VGPRs) MFMA A/B frag
typedef __attribute__((ext_vector_type(4))) float  floatx4;  // MFMA C/D frag / f32 vec4

// fp32 -> bf16 round-to-nearest-even (inputs are cos/sin, never NaN/inf)
static __device__ __forceinline__ unsigned short f2bf(float f) {
    union { float f; unsigned u; } x; x.f = f;
    return (unsigned short)((x.u + 0x7fffu + ((x.u >> 16) & 1u)) >> 16);
}

// Pack phases -> [cos(64) | sin(64)] bf16 rows. blockIdx.y selects q/k tensor.
// One thread handles 4 consecutive harmonics (float4 load, 2x ushort4 stores).
__global__ void sincos_pack_kernel(const float* __restrict__ pq,
                                   const float* __restrict__ pk,
                                   unsigned short* __restrict__ qpack,
                                   unsigned short* __restrict__ kpack) {
    int i = blockIdx.x * blockDim.x + threadIdx.x;     // group of 4 elements
    const float* src = blockIdx.y ? pk : pq;
    unsigned short* dst = blockIdx.y ? kpack : qpack;
    float4 v = ((const float4*)src)[i];
    int base = i << 2;
    int row  = base >> 6;      // / NH
    int h    = base & 63;      // % NH  (multiple of 4)
    float s0, c0, s1, c1, s2, c2, s3, c3;
    __sincosf(v.x, &s0, &c0);
    __sincosf(v.y, &s1, &c1);
    __sincosf(v.z, &s2, &c2);
    __sincosf(v.w, &s3, &c3);
    ushort4 cu; cu.x = f2bf(c0); cu.y = f2bf(c1); cu.z = f2bf(c2); cu.w = f2bf(c3);
    ushort4 su; su.x = f2bf(s0); su.y = f2bf(s1); su.z = f2bf(s2); su.w = f2bf(s3);
    unsigned short* p = dst + (size_t)row * KP + h;
    *(ushort4*)p        = cu;      // cos block
    *(ushort4*)(p + NH) = su;      // sin block
}

// Batched GEMM: C[b] = Qp[b] (2048x128) @ Kp[b]^T (128x2048) * (1/64).
// 128x128 C-tile per block, 4 waves of 64x64, K=128 staged once into LDS via
// global_load_lds (width 16), XOR-swizzled on the *global source* chunk index.
// Epilogue: per-wave LDS transpose of each 16x64 C slab -> float4 nontemporal
// stores (256B contiguous per 16-lane group, 1KB per wave-instr — the same
// access shape as fillBufferAligned, which sustains ~5.9 TB/s on this chip).
__global__ __launch_bounds__(256, 2)
void coherence_gemm_kernel(const unsigned short* __restrict__ Qp,
                           const unsigned short* __restrict__ Kp,
                           float* __restrict__ out) {
    // One 64 KB array: [A tile | B tile] during GEMM, f32 staging in epilogue.
    __shared__ unsigned short ABs[2 * 128 * KP];
    unsigned short* As = ABs;
    unsigned short* Bs = ABs + 128 * KP;
    const int b  = blockIdx.z;
    const int tm = blockIdx.y;
    const int tn = blockIdx.x;
    const int tid  = threadIdx.x;
    const int wave = tid >> 6;
    const int lane = tid & 63;

    // ---- stage: each wave loads 32 rows of A and 32 of B, 4 rows / instr ----
    const size_t qbase = (size_t)b * SEQ * KP + (size_t)tm * 128 * KP;
    const size_t kbase = (size_t)b * SEQ * KP + (size_t)tn * 128 * KP;
    const int subrow = lane >> 4;    // 0..3 row within the 4-row group
    const int cslot  = lane & 15;    // 16-byte chunk slot within the row
    for (int it = 0; it < 8; ++it) {
        const int rg = wave * 32 + it * 4;          // first row of this group
        const int r  = rg + subrow;                 // this lane's row (0..127)
        const int cg = cslot ^ (r & 7);             // swizzled source chunk
        const unsigned short* gA = Qp + qbase + (size_t)r * KP + cg * 8;
        const unsigned short* gB = Kp + kbase + (size_t)r * KP + cg * 8;
        unsigned short* lA = As + rg * KP;          // wave-uniform LDS base
        unsigned short* lB = Bs + rg * KP;
        __builtin_amdgcn_global_load_lds(
            (const __attribute__((address_space(1))) void*)gA,
            (__attribute__((address_space(3))) void*)lA, 16, 0, 0);
        __builtin_amdgcn_global_load_lds(
            (const __attribute__((address_space(1))) void*)gB,
            (__attribute__((address_space(3))) void*)lB, 16, 0, 0);
    }
    __syncthreads();

    // ---- compute: wave (wr,wc) owns C rows wr*64.., cols wc*64.. ----
    const int wr = wave >> 1, wc = wave & 1;
    const int qlane = lane >> 4;    // quad 0..3
    const int mrow  = lane & 15;

    floatx4 acc[4][4] = {};
    #pragma unroll
    for (int ks = 0; ks < 4; ++ks) {            // K steps of 32
        short8 af[4], bf[4];
        #pragma unroll
        for (int im = 0; im < 4; ++im) {
            const int m = wr * 64 + im * 16 + mrow;
            const int chunk = (ks * 4 + qlane) ^ (m & 7);
            af[im] = *(const short8*)(As + m * KP + chunk * 8);
        }
        #pragma unroll
        for (int in = 0; in < 4; ++in) {
            const int n = wc * 64 + in * 16 + mrow;
            const int chunk = (ks * 4 + qlane) ^ (n & 7);
            bf[in] = *(const short8*)(Bs + n * KP + chunk * 8);
        }
        #pragma unroll
        for (int im = 0; im < 4; ++im)
            #pragma unroll
            for (int in = 0; in < 4; ++in)
                acc[im][in] = __builtin_amdgcn_mfma_f32_16x16x32_bf16(
                    af[im], bf[in], acc[im][in], 0, 0, 0);
    }

    __syncthreads();   // all waves done reading ABs -> safe to reuse as staging

    // ---- epilogue: LDS-transpose each 16x64 slab, store float4 rows ----
    // C/D frag layout: col = mrow, row = qlane*4 + j. Write the slab into
    // staging at [row][col], read back 4 rows x 16 float4/row per pass.
    // Two slabs per wave (alternate on im) to decouple WAR across iterations.
    float* st = reinterpret_cast<float*>(ABs) + wave * 2 * STSZ;  // 8704 B/wave
    const size_t obase = (size_t)b * SEQ * SEQ + (size_t)(tm * 128) * SEQ + tn * 128;
    const float scale = 1.0f / 64.0f;
    #pragma unroll
    for (int im = 0; im < 4; ++im) {
        float* sb = st + (im & 1) * STSZ;
        #pragma unroll
        for (int in = 0; in < 4; ++in)
            #pragma unroll
            for (int j = 0; j < 4; ++j)
                sb[(qlane * 4 + j) * STLD + in * 16 + mrow] = acc[im][in][j] * scale;
        asm volatile("s_waitcnt lgkmcnt(0)" ::: "memory");   // writes visible to our reads
        const size_t rbase = obase + (size_t)(wr * 64 + im * 16) * SEQ
                           + (size_t)(wc * 64 + mrow * 4);
        #pragma unroll
        for (int p = 0; p < 4; ++p) {
            const int rr = p * 4 + qlane;                    // row 0..15 of the slab
            const floatx4 v = *(const floatx4*)(sb + rr * STLD + mrow * 4);
            __builtin_nontemporal_store(v, (floatx4*)(out + rbase + (size_t)rr * SEQ));
        }
    }
}

extern "C" void kernel_launch(void* const* d_in, const int* in_sizes, int n_in,
                              void* d_out, int out_size, void* d_ws, size_t ws_size,
                              hipStream_t stream) {
    const float* pq = (const float*)d_in[0];
    const float* pk = (const float*)d_in[1];
    float* out = (float*)d_out;

    unsigned short* qpack = (unsigned short*)d_ws;                 // 8 MiB
    unsigned short* kpack = qpack + (size_t)NBATCH * SEQ * KP;     // 8 MiB

    // pack: NBATCH*SEQ*NH / 4 threads per tensor = 524288; y dim selects q/k
    const int n4 = NBATCH * SEQ * NH / 4;
    dim3 pgrid(n4 / 256, 2, 1);
    sincos_pack_kernel<<<pgrid, 256, 0, stream>>>(pq, pk, qpack, kpack);

    dim3 ggrid(SEQ / 128, SEQ / 128, NBATCH);   // (16,16,16)
    coherence_gemm_kernel<<<ggrid, 256, 0, stream>>>(qpack, kpack, out);
}